// Round 1
// baseline (6550.777 us; speedup 1.0000x reference)
//
#include <hip/hip_runtime.h>
#include <hip/hip_bf16.h>
#include <math.h>

#define NLAYER 12
#define BB 8
#define SS 512
#define HH 768
#define NHEAD 12
#define DHEAD 64
#define FFDIM 3072
#define MROWS (BB*SS)   // 4096

typedef __attribute__((ext_vector_type(8))) short bf16x8;
typedef __attribute__((ext_vector_type(4))) float f32x4;

__device__ __forceinline__ short f2bf(float f){
  union { float f; unsigned u; } v; v.f = f;
  unsigned r = (v.u + 0x7fffu + ((v.u >> 16) & 1u)) >> 16;
  return (short)(unsigned short)r;
}
__device__ __forceinline__ float bf2f(short s){
  union { unsigned u; float f; } v; v.u = ((unsigned)(unsigned short)s) << 16; return v.f;
}

// ---------------------------------------------------------------------------
// Generic tiled GEMM: out[M,N] = A(bf16)[M,K] @ W(f32)[K,N] + bias, epilogues:
// EPI 0: out bf16 = acc + bias
// EPI 1: out bf16 = gelu_exact(acc + bias)
// EPI 2: out f32  = acc + bias + res
// Tile 128x128x32, 4 waves (2x2), each wave 64x64 via 4x4 mfma_16x16x32 frags.
// ---------------------------------------------------------------------------
template<int EPI>
__global__ __launch_bounds__(256) void gemm_bf16(
    const short* __restrict__ A, const float* __restrict__ W,
    const float* __restrict__ bias, const float* __restrict__ res,
    void* __restrict__ outp, int M, int N, int K)
{
  __shared__ __align__(16) short Asm[128][40];
  __shared__ __align__(16) short Bsm[128][40];   // W^T tile: Bsm[n][k]
  const int tid  = threadIdx.x;
  const int lane = tid & 63;
  const int wid  = tid >> 6;
  const int wm   = wid >> 1, wn = wid & 1;
  const int row0 = blockIdx.x * 128, col0 = blockIdx.y * 128;

  f32x4 acc[4][4] = {};

  for (int k0 = 0; k0 < K; k0 += 32) {
    // stage A tile (bf16, straight copy): 128x32, 16B per thread x2 passes
    #pragma unroll
    for (int p = 0; p < 2; ++p) {
      int idx = p*256 + tid;
      int r = idx >> 2, c = (idx & 3) << 3;
      *reinterpret_cast<int4*>(&Asm[r][c]) =
        *reinterpret_cast<const int4*>(A + (size_t)(row0 + r)*K + k0 + c);
    }
    // stage B tile: read W f32 rows coalesced, convert, write transposed
    #pragma unroll
    for (int p = 0; p < 4; ++p) {
      int kr = (tid >> 5) + p*8;          // 0..31
      int nc = (tid & 31) << 2;           // 0..124
      float4 w = *reinterpret_cast<const float4*>(W + (size_t)(k0 + kr)*N + col0 + nc);
      Bsm[nc+0][kr] = f2bf(w.x);
      Bsm[nc+1][kr] = f2bf(w.y);
      Bsm[nc+2][kr] = f2bf(w.z);
      Bsm[nc+3][kr] = f2bf(w.w);
    }
    __syncthreads();
    bf16x8 af[4], bfr[4];
    #pragma unroll
    for (int i=0;i<4;i++)
      af[i] = *reinterpret_cast<const bf16x8*>(&Asm[wm*64 + i*16 + (lane&15)][(lane>>4)*8]);
    #pragma unroll
    for (int j=0;j<4;j++)
      bfr[j] = *reinterpret_cast<const bf16x8*>(&Bsm[wn*64 + j*16 + (lane&15)][(lane>>4)*8]);
    #pragma unroll
    for (int i=0;i<4;i++)
      #pragma unroll
      for (int j=0;j<4;j++)
        acc[i][j] = __builtin_amdgcn_mfma_f32_16x16x32_bf16(af[i], bfr[j], acc[i][j], 0,0,0);
    __syncthreads();
  }

  #pragma unroll
  for (int i=0;i<4;i++){
    int gr0 = row0 + wm*64 + i*16 + ((lane>>4)<<2);
    #pragma unroll
    for (int j=0;j<4;j++){
      int gc = col0 + wn*64 + j*16 + (lane&15);
      float bv = bias[gc];
      #pragma unroll
      for (int r=0;r<4;r++){
        float v = acc[i][j][r] + bv;
        size_t o = (size_t)(gr0 + r)*N + gc;
        if constexpr (EPI == 1) {
          v = 0.5f*v*(1.0f + erff(v*0.70710678118654752f));
          reinterpret_cast<short*>(outp)[o] = f2bf(v);
        } else if constexpr (EPI == 2) {
          v += res[o];
          reinterpret_cast<float*>(outp)[o] = v;
        } else {
          reinterpret_cast<short*>(outp)[o] = f2bf(v);
        }
      }
    }
  }
}

// ---------------------------------------------------------------------------
// scores[bh,q,k] = (Q[b,q,h,:] . K[b,k,h,:]) * 0.125 + mask[b,k]  (bf16 out)
// block: 64x64 tile of one (b,h); 4 waves 2x2, each 32x32.
// ---------------------------------------------------------------------------
__global__ __launch_bounds__(256) void attn_scores(
    const short* __restrict__ Q, const short* __restrict__ Kt,
    const float* __restrict__ mask, short* __restrict__ Sc)
{
  __shared__ __align__(16) short Qs[64][72];
  __shared__ __align__(16) short Ks[64][72];
  const int tid = threadIdx.x, lane = tid & 63, wid = tid >> 6;
  const int wm = wid >> 1, wn = wid & 1;
  const int qt = blockIdx.x, kt = blockIdx.y, bh = blockIdx.z;
  const int b = bh / NHEAD, h = bh % NHEAD;
  {
    int r = tid >> 2, c = (tid & 3) << 4;
    const int4* qsrc = reinterpret_cast<const int4*>(Q  + (size_t)(b*SS + qt*64 + r)*HH + h*DHEAD + c);
    const int4* ksrc = reinterpret_cast<const int4*>(Kt + (size_t)(b*SS + kt*64 + r)*HH + h*DHEAD + c);
    *reinterpret_cast<int4*>(&Qs[r][c])   = qsrc[0];
    *reinterpret_cast<int4*>(&Qs[r][c+8]) = qsrc[1];
    *reinterpret_cast<int4*>(&Ks[r][c])   = ksrc[0];
    *reinterpret_cast<int4*>(&Ks[r][c+8]) = ksrc[1];
  }
  __syncthreads();
  f32x4 acc[2][2] = {};
  #pragma unroll
  for (int d0=0; d0<64; d0+=32){
    bf16x8 qa[2], kb[2];
    #pragma unroll
    for (int i=0;i<2;i++)
      qa[i] = *reinterpret_cast<const bf16x8*>(&Qs[wm*32 + i*16 + (lane&15)][d0 + (lane>>4)*8]);
    #pragma unroll
    for (int j=0;j<2;j++)
      kb[j] = *reinterpret_cast<const bf16x8*>(&Ks[wn*32 + j*16 + (lane&15)][d0 + (lane>>4)*8]);
    #pragma unroll
    for (int i=0;i<2;i++)
      #pragma unroll
      for (int j=0;j<2;j++)
        acc[i][j] = __builtin_amdgcn_mfma_f32_16x16x32_bf16(qa[i], kb[j], acc[i][j], 0,0,0);
  }
  #pragma unroll
  for (int i=0;i<2;i++){
    int gq0 = qt*64 + wm*32 + i*16 + ((lane>>4)<<2);
    #pragma unroll
    for (int j=0;j<2;j++){
      int gk = kt*64 + wn*32 + j*16 + (lane&15);
      float mv = mask[b*SS + gk];
      #pragma unroll
      for (int r=0;r<4;r++){
        float v = acc[i][j][r]*0.125f + mv;
        Sc[((size_t)bh*SS + gq0 + r)*SS + gk] = f2bf(v);
      }
    }
  }
}

// in-place softmax over rows of 512 bf16; one wave per row, 4 rows/block
__global__ __launch_bounds__(256) void softmax_rows(short* __restrict__ Sc)
{
  const int lane = threadIdx.x & 63;
  const size_t row = (size_t)blockIdx.x*4 + (threadIdx.x >> 6);
  short* p = Sc + row*SS + lane*8;
  union { int4 v; short s[8]; } u;
  u.v = *reinterpret_cast<const int4*>(p);
  float f[8];
  #pragma unroll
  for (int j=0;j<8;j++) f[j] = bf2f(u.s[j]);
  float m = f[0];
  #pragma unroll
  for (int j=1;j<8;j++) m = fmaxf(m, f[j]);
  #pragma unroll
  for (int off=32; off>0; off>>=1) m = fmaxf(m, __shfl_xor(m, off));
  float sum = 0.f;
  #pragma unroll
  for (int j=0;j<8;j++){ f[j] = __expf(f[j]-m); sum += f[j]; }
  #pragma unroll
  for (int off=32; off>0; off>>=1) sum += __shfl_xor(sum, off);
  float inv = 1.0f / sum;
  #pragma unroll
  for (int j=0;j<8;j++) u.s[j] = f2bf(f[j]*inv);
  *reinterpret_cast<int4*>(p) = u.v;
}

// ctx[b,q,h,:] = P[bh,q,:] @ V[b,:,h,:]; block: 64 q-rows of one (b,h)
__global__ __launch_bounds__(256) void attn_pv(
    const short* __restrict__ P, const short* __restrict__ V, short* __restrict__ ctx)
{
  __shared__ __align__(16) short Ps[64][72];
  __shared__ __align__(16) short Vt[64][72];   // Vt[d][k]
  const int tid = threadIdx.x, lane = tid & 63, w = tid >> 6;
  const int qt = blockIdx.x, bh = blockIdx.y;
  const int b = bh / NHEAD, h = bh % NHEAD;
  f32x4 acc[4] = {};
  for (int k0=0; k0<SS; k0+=64){
    int r = tid >> 2, c = (tid & 3) << 4;
    const int4* ps = reinterpret_cast<const int4*>(P + ((size_t)bh*SS + qt*64 + r)*SS + k0 + c);
    *reinterpret_cast<int4*>(&Ps[r][c])   = ps[0];
    *reinterpret_cast<int4*>(&Ps[r][c+8]) = ps[1];
    union {int4 v; short s[8];} a0, a1;
    const int4* vs = reinterpret_cast<const int4*>(V + (size_t)(b*SS + k0 + r)*HH + h*DHEAD + c);
    a0.v = vs[0]; a1.v = vs[1];
    #pragma unroll
    for (int e=0;e<8;e++){ Vt[c+e][r] = a0.s[e]; Vt[c+8+e][r] = a1.s[e]; }
    __syncthreads();
    #pragma unroll
    for (int kk=0; kk<64; kk+=32){
      bf16x8 pa = *reinterpret_cast<const bf16x8*>(&Ps[w*16 + (lane&15)][kk + (lane>>4)*8]);
      #pragma unroll
      for (int j=0;j<4;j++){
        bf16x8 vb = *reinterpret_cast<const bf16x8*>(&Vt[j*16 + (lane&15)][kk + (lane>>4)*8]);
        acc[j] = __builtin_amdgcn_mfma_f32_16x16x32_bf16(pa, vb, acc[j], 0,0,0);
      }
    }
    __syncthreads();
  }
  #pragma unroll
  for (int j=0;j<4;j++){
    int d = j*16 + (lane&15);
    #pragma unroll
    for (int r=0;r<4;r++){
      int q = qt*64 + w*16 + ((lane>>4)<<2) + r;
      ctx[(size_t)(b*SS + q)*HH + h*DHEAD + d] = f2bf(acc[j][r]);
    }
  }
}

// row LayerNorm, writes f32 (residual path) + bf16 (GEMM A operand); in-place safe
__global__ __launch_bounds__(256) void layernorm_dual(
    const float* __restrict__ x, const float* __restrict__ g, const float* __restrict__ bta,
    float* __restrict__ outF, short* __restrict__ outBF)
{
  const int row = blockIdx.x, t = threadIdx.x;
  const float* xr = x + (size_t)row*HH;
  float v0 = xr[t], v1 = xr[t+256], v2 = xr[t+512];
  float s = v0+v1+v2, q = v0*v0+v1*v1+v2*v2;
  #pragma unroll
  for (int off=32; off>0; off>>=1){ s += __shfl_xor(s,off); q += __shfl_xor(q,off); }
  __shared__ float ss[4], qq[4];
  if ((t&63)==0){ ss[t>>6]=s; qq[t>>6]=q; }
  __syncthreads();
  s = ss[0]+ss[1]+ss[2]+ss[3];
  q = qq[0]+qq[1]+qq[2]+qq[3];
  const float mu = s*(1.0f/HH);
  float var = q*(1.0f/HH) - mu*mu;
  const float rstd = rsqrtf(var + 1e-12f);
  float* oF = outF + (size_t)row*HH;
  short* oB = outBF + (size_t)row*HH;
  float vv[3] = {v0,v1,v2};
  #pragma unroll
  for (int e=0;e<3;e++){
    int c = t + e*256;
    float y = (vv[e]-mu)*rstd*g[c] + bta[c];
    oF[c] = y; oB[c] = f2bf(y);
  }
}

__global__ __launch_bounds__(256) void cvt_f32_bf16(
    const float* __restrict__ in, short* __restrict__ out, int n4)
{
  int i = blockIdx.x*256 + threadIdx.x;
  if (i >= n4) return;
  float4 f = reinterpret_cast<const float4*>(in)[i];
  short4 o; o.x=f2bf(f.x); o.y=f2bf(f.y); o.z=f2bf(f.z); o.w=f2bf(f.w);
  reinterpret_cast<short4*>(out)[i] = o;
}

extern "C" void kernel_launch(void* const* d_in, const int* in_sizes, int n_in,
                              void* d_out, int out_size, void* d_ws, size_t ws_size,
                              hipStream_t stream)
{
  const float* hs   = (const float*)d_in[0];
  const float* mask = (const float*)d_in[1];
  const float* Wq = (const float*)d_in[2];
  const float* bq = (const float*)d_in[3];
  const float* Wk = (const float*)d_in[4];
  const float* bk = (const float*)d_in[5];
  const float* Wv = (const float*)d_in[6];
  const float* bv = (const float*)d_in[7];
  const float* Wo = (const float*)d_in[8];
  const float* bo = (const float*)d_in[9];
  const float* g1 = (const float*)d_in[10];
  const float* b1 = (const float*)d_in[11];
  const float* Wi = (const float*)d_in[12];
  const float* bi = (const float*)d_in[13];
  const float* Wo2= (const float*)d_in[14];
  const float* bo2= (const float*)d_in[15];
  const float* g2 = (const float*)d_in[16];
  const float* b2 = (const float*)d_in[17];

  char* ws = (char*)d_ws;
  size_t off = 0;
  auto alloc = [&](size_t bytes)->char* {
    char* p = ws + off; off += (bytes + 255) & ~(size_t)255; return p;
  };
  float* hf0  = (float*)alloc((size_t)MROWS*HH*4);
  float* hf1  = (float*)alloc((size_t)MROWS*HH*4);
  short* bfA  = (short*)alloc((size_t)MROWS*HH*2);
  short* bfB  = (short*)alloc((size_t)MROWS*HH*2);
  short* Qb   = (short*)alloc((size_t)MROWS*HH*2);
  short* Kb   = (short*)alloc((size_t)MROWS*HH*2);
  short* Vb   = (short*)alloc((size_t)MROWS*HH*2);
  short* Sc   = (short*)alloc((size_t)BB*NHEAD*SS*SS*2);
  short* ctx  = (short*)alloc((size_t)MROWS*HH*2);
  short* inter= (short*)alloc((size_t)MROWS*FFDIM*2);

  cvt_f32_bf16<<<dim3(3072), dim3(256), 0, stream>>>(hs, bfA, MROWS*HH/4);

  const float* curF = hs;
  short* curBF = bfA;
  for (int l=0; l<NLAYER; ++l){
    float* pre1  = (curF == hf0) ? hf1 : hf0;
    short* attBF = (curBF == bfA) ? bfB : bfA;
    size_t wo = (size_t)l*HH*HH, vb_ = (size_t)l*HH;

    gemm_bf16<0><<<dim3(32,6), 256, 0, stream>>>(curBF, Wq+wo, bq+vb_, nullptr, Qb, MROWS, HH, HH);
    gemm_bf16<0><<<dim3(32,6), 256, 0, stream>>>(curBF, Wk+wo, bk+vb_, nullptr, Kb, MROWS, HH, HH);
    gemm_bf16<0><<<dim3(32,6), 256, 0, stream>>>(curBF, Wv+wo, bv+vb_, nullptr, Vb, MROWS, HH, HH);

    attn_scores<<<dim3(8,8,BB*NHEAD), 256, 0, stream>>>(Qb, Kb, mask, Sc);
    softmax_rows<<<dim3(BB*NHEAD*SS/4), 256, 0, stream>>>(Sc);
    attn_pv<<<dim3(8,BB*NHEAD), 256, 0, stream>>>(Sc, Vb, ctx);

    gemm_bf16<2><<<dim3(32,6), 256, 0, stream>>>(ctx, Wo+wo, bo+vb_, curF, pre1, MROWS, HH, HH);
    layernorm_dual<<<dim3(MROWS), 256, 0, stream>>>(pre1, g1+vb_, b1+vb_, pre1, attBF);

    gemm_bf16<1><<<dim3(32,24), 256, 0, stream>>>(attBF, Wi+(size_t)l*HH*FFDIM, bi+(size_t)l*FFDIM,
                                                  nullptr, inter, MROWS, FFDIM, HH);
    float* pre2 = (pre1 == hf0) ? hf1 : hf0;
    gemm_bf16<2><<<dim3(32,6), 256, 0, stream>>>(inter, Wo2+(size_t)l*FFDIM*HH, bo2+vb_, pre1, pre2,
                                                 MROWS, HH, FFDIM);
    short* nextBF = (attBF == bfA) ? bfB : bfA;
    float* lnout = (l == NLAYER-1) ? (float*)d_out : pre2;
    layernorm_dual<<<dim3(MROWS), 256, 0, stream>>>(pre2, g2+vb_, b2+vb_, lnout, nextBF);
    curF = lnout; curBF = nextBF;
  }
}

// Round 3
// 3017.844 us; speedup vs baseline: 2.1707x; 2.1707x over previous
//
#include <hip/hip_runtime.h>
#include <hip/hip_bf16.h>
#include <math.h>

#define NLAYER 12
#define BB 8
#define SS 512
#define HH 768
#define NHEAD 12
#define DHEAD 64
#define FFDIM 3072
#define MROWS (BB*SS)   // 4096
#define QKVN (3*HH)     // 2304

typedef __attribute__((ext_vector_type(8))) short bf16x8;
typedef __attribute__((ext_vector_type(4))) float f32x4;

__device__ __forceinline__ short f2bf(float f){
  union { float f; unsigned u; } v; v.f = f;
  unsigned r = (v.u + 0x7fffu + ((v.u >> 16) & 1u)) >> 16;
  return (short)(unsigned short)r;
}
__device__ __forceinline__ float bf2f(short s){
  union { unsigned u; float f; } v; v.u = ((unsigned)(unsigned short)s) << 16; return v.f;
}

__device__ __forceinline__ void gload_lds16(const void* g, void* l){
  __builtin_amdgcn_global_load_lds(
      (const __attribute__((address_space(1))) void*)g,
      (__attribute__((address_space(3))) void*)l, 16, 0, 0);
}

// ---------------------------------------------------------------------------
// m97-structure GEMM: out[M,N] = A(bf16)[M,K] @ Bt(bf16)[N,K]^T + bias
// BK=32, 4 waves (2x2), per-wave tile (BM/2)x(BN/2), global_load_lds staging,
// linear LDS, ds_read_b128 fragments.
// EPI 0: bf16 = acc + bias ; EPI 1: bf16 = gelu(acc+bias) ; EPI 2: f32 = acc+bias+res
// ---------------------------------------------------------------------------
template<int BM, int BN, int EPI>
__global__ __launch_bounds__(256) void gemm_tn(
    const short* __restrict__ A, const short* __restrict__ Bt,
    const float* __restrict__ bias, const float* __restrict__ res,
    void* __restrict__ outp, int M, int N, int K)
{
  constexpr int MI = BM/32;   // fragment rows per wave
  constexpr int NI = BN/32;   // fragment cols per wave
  __shared__ __align__(16) short As[BM*32];
  __shared__ __align__(16) short Bs[BN*32];
  const int tid = threadIdx.x, lane = tid & 63, w = tid >> 6;
  const int wm = w >> 1, wn = w & 1;
  const int row0 = blockIdx.x * BM, col0 = blockIdx.y * BN;
  const short* Ab = A  + (size_t)row0*K + (lane&3)*8;
  const short* Bb = Bt + (size_t)col0*K + (lane&3)*8;

  f32x4 acc[MI][NI] = {};

  for (int k0 = 0; k0 < K; k0 += 32){
    #pragma unroll
    for (int p = 0; p < BM/64; ++p){
      int r = w*(BM/4) + p*16 + (lane>>2);
      gload_lds16(Ab + (size_t)r*K + k0, &As[(w*(BM/4) + p*16)*32]);
    }
    #pragma unroll
    for (int p = 0; p < BN/64; ++p){
      int r = w*(BN/4) + p*16 + (lane>>2);
      gload_lds16(Bb + (size_t)r*K + k0, &Bs[(w*(BN/4) + p*16)*32]);
    }
    __syncthreads();
    bf16x8 af[MI], bfr[NI];
    #pragma unroll
    for (int i=0;i<MI;i++)
      af[i] = *reinterpret_cast<const bf16x8*>(&As[(wm*(BM/2) + i*16 + (lane&15))*32 + (lane>>4)*8]);
    #pragma unroll
    for (int j=0;j<NI;j++)
      bfr[j] = *reinterpret_cast<const bf16x8*>(&Bs[(wn*(BN/2) + j*16 + (lane&15))*32 + (lane>>4)*8]);
    #pragma unroll
    for (int i=0;i<MI;i++)
      #pragma unroll
      for (int j=0;j<NI;j++)
        acc[i][j] = __builtin_amdgcn_mfma_f32_16x16x32_bf16(af[i], bfr[j], acc[i][j], 0,0,0);
    __syncthreads();
  }

  #pragma unroll
  for (int i=0;i<MI;i++){
    int gr0 = row0 + wm*(BM/2) + i*16 + ((lane>>4)<<2);
    #pragma unroll
    for (int j=0;j<NI;j++){
      int gc = col0 + wn*(BN/2) + j*16 + (lane&15);
      float bv = bias[gc];
      #pragma unroll
      for (int r=0;r<4;r++){
        float v = acc[i][j][r] + bv;
        size_t o = (size_t)(gr0 + r)*N + gc;
        if constexpr (EPI == 1) {
          v = 0.5f*v*(1.0f + erff(v*0.70710678118654752f));
          reinterpret_cast<short*>(outp)[o] = f2bf(v);
        } else if constexpr (EPI == 2) {
          v += res[o];
          reinterpret_cast<float*>(outp)[o] = v;
        } else {
          reinterpret_cast<short*>(outp)[o] = f2bf(v);
        }
      }
    }
  }
}

// ---------------------------------------------------------------------------
// Weight transpose + convert: src f32 [K][N] (layer-strided) -> dst bf16 [N][K]
// 64x64 tiles. grid = (N/64, K/64, NLAYER)
// ---------------------------------------------------------------------------
__global__ __launch_bounds__(256) void transpose_w(
    const float* __restrict__ src, short* __restrict__ dst,
    int K, int N, size_t srcLS, size_t dstLS, size_t dstOff)
{
  __shared__ float T[64][65];
  const int l = blockIdx.z;
  const float* s = src + (size_t)l*srcLS;
  short* d = dst + (size_t)l*dstLS + dstOff;
  const int n0 = blockIdx.x*64, k0 = blockIdx.y*64;
  const int tr = threadIdx.x >> 4;
  const int tc = (threadIdx.x & 15) * 4;
  #pragma unroll
  for (int p=0;p<4;p++){
    float4 v = *reinterpret_cast<const float4*>(s + (size_t)(k0 + p*16 + tr)*N + n0 + tc);
    T[p*16+tr][tc+0]=v.x; T[p*16+tr][tc+1]=v.y; T[p*16+tr][tc+2]=v.z; T[p*16+tr][tc+3]=v.w;
  }
  __syncthreads();
  const int rn = threadIdx.x >> 2;
  const int ck = (threadIdx.x & 3) * 16;
  union { int4 v[2]; short s[16]; } o;
  #pragma unroll
  for (int e=0;e<16;e++) o.s[e] = f2bf(T[ck+e][rn]);
  int4* dp = reinterpret_cast<int4*>(d + (size_t)(n0+rn)*K + k0 + ck);
  dp[0] = o.v[0]; dp[1] = o.v[1];
}

__global__ __launch_bounds__(256) void pack_bias(
    const float* __restrict__ bq, const float* __restrict__ bk,
    const float* __restrict__ bv, float* __restrict__ bqkv)
{
  int i = blockIdx.x*256 + threadIdx.x;
  if (i >= NLAYER*QKVN) return;
  int l = i / QKVN, c = i % QKVN;
  float v = (c < HH) ? bq[l*HH + c] : (c < 2*HH) ? bk[l*HH + c - HH] : bv[l*HH + c - 2*HH];
  bqkv[i] = v;
}

// ---------------------------------------------------------------------------
// scores[bh,q,k] = (Q . K) * 0.125 + mask ; Q,K at row stride ld (QKV fused)
// ---------------------------------------------------------------------------
__global__ __launch_bounds__(256) void attn_scores(
    const short* __restrict__ Q, const short* __restrict__ Kt,
    const float* __restrict__ mask, short* __restrict__ Sc, int ld)
{
  __shared__ __align__(16) short Qs[64][72];
  __shared__ __align__(16) short Ks[64][72];
  const int tid = threadIdx.x, lane = tid & 63, wid = tid >> 6;
  const int wm = wid >> 1, wn = wid & 1;
  const int qt = blockIdx.x, kt = blockIdx.y, bh = blockIdx.z;
  const int b = bh / NHEAD, h = bh % NHEAD;
  {
    int r = tid >> 2, c = (tid & 3) << 4;
    const int4* qsrc = reinterpret_cast<const int4*>(Q  + (size_t)(b*SS + qt*64 + r)*ld + h*DHEAD + c);
    const int4* ksrc = reinterpret_cast<const int4*>(Kt + (size_t)(b*SS + kt*64 + r)*ld + h*DHEAD + c);
    *reinterpret_cast<int4*>(&Qs[r][c])   = qsrc[0];
    *reinterpret_cast<int4*>(&Qs[r][c+8]) = qsrc[1];
    *reinterpret_cast<int4*>(&Ks[r][c])   = ksrc[0];
    *reinterpret_cast<int4*>(&Ks[r][c+8]) = ksrc[1];
  }
  __syncthreads();
  f32x4 acc[2][2] = {};
  #pragma unroll
  for (int d0=0; d0<64; d0+=32){
    bf16x8 qa[2], kb[2];
    #pragma unroll
    for (int i=0;i<2;i++)
      qa[i] = *reinterpret_cast<const bf16x8*>(&Qs[wm*32 + i*16 + (lane&15)][d0 + (lane>>4)*8]);
    #pragma unroll
    for (int j=0;j<2;j++)
      kb[j] = *reinterpret_cast<const bf16x8*>(&Ks[wn*32 + j*16 + (lane&15)][d0 + (lane>>4)*8]);
    #pragma unroll
    for (int i=0;i<2;i++)
      #pragma unroll
      for (int j=0;j<2;j++)
        acc[i][j] = __builtin_amdgcn_mfma_f32_16x16x32_bf16(qa[i], kb[j], acc[i][j], 0,0,0);
  }
  #pragma unroll
  for (int i=0;i<2;i++){
    int gq0 = qt*64 + wm*32 + i*16 + ((lane>>4)<<2);
    #pragma unroll
    for (int j=0;j<2;j++){
      int gk = kt*64 + wn*32 + j*16 + (lane&15);
      float mv = mask[b*SS + gk];
      #pragma unroll
      for (int r=0;r<4;r++){
        float v = acc[i][j][r]*0.125f + mv;
        Sc[((size_t)bh*SS + gq0 + r)*SS + gk] = f2bf(v);
      }
    }
  }
}

// in-place softmax over rows of 512 bf16; one wave per row, 4 rows/block
__global__ __launch_bounds__(256) void softmax_rows(short* __restrict__ Sc)
{
  const int lane = threadIdx.x & 63;
  const size_t row = (size_t)blockIdx.x*4 + (threadIdx.x >> 6);
  short* p = Sc + row*SS + lane*8;
  union { int4 v; short s[8]; } u;
  u.v = *reinterpret_cast<const int4*>(p);
  float f[8];
  #pragma unroll
  for (int j=0;j<8;j++) f[j] = bf2f(u.s[j]);
  float m = f[0];
  #pragma unroll
  for (int j=1;j<8;j++) m = fmaxf(m, f[j]);
  #pragma unroll
  for (int off=32; off>0; off>>=1) m = fmaxf(m, __shfl_xor(m, off));
  float sum = 0.f;
  #pragma unroll
  for (int j=0;j<8;j++){ f[j] = __expf(f[j]-m); sum += f[j]; }
  #pragma unroll
  for (int off=32; off>0; off>>=1) sum += __shfl_xor(sum, off);
  float inv = 1.0f / sum;
  #pragma unroll
  for (int j=0;j<8;j++) u.s[j] = f2bf(f[j]*inv);
  *reinterpret_cast<int4*>(p) = u.v;
}

// ctx[b,q,h,:] = P[bh,q,:] @ V[b,:,h,:] ; V at row stride ld
__global__ __launch_bounds__(256) void attn_pv(
    const short* __restrict__ P, const short* __restrict__ V, short* __restrict__ ctx, int ld)
{
  __shared__ __align__(16) short Ps[64][72];
  __shared__ __align__(16) short Vt[64][72];   // Vt[d][k]
  const int tid = threadIdx.x, lane = tid & 63, w = tid >> 6;
  const int qt = blockIdx.x, bh = blockIdx.y;
  const int b = bh / NHEAD, h = bh % NHEAD;
  f32x4 acc[4] = {};
  for (int k0=0; k0<SS; k0+=64){
    int r = tid >> 2, c = (tid & 3) << 4;
    const int4* ps = reinterpret_cast<const int4*>(P + ((size_t)bh*SS + qt*64 + r)*SS + k0 + c);
    *reinterpret_cast<int4*>(&Ps[r][c])   = ps[0];
    *reinterpret_cast<int4*>(&Ps[r][c+8]) = ps[1];
    union {int4 v; short s[8];} a0, a1;
    const int4* vs = reinterpret_cast<const int4*>(V + (size_t)(b*SS + k0 + r)*ld + h*DHEAD + c);
    a0.v = vs[0]; a1.v = vs[1];
    #pragma unroll
    for (int e=0;e<8;e++){ Vt[c+e][r] = a0.s[e]; Vt[c+8+e][r] = a1.s[e]; }
    __syncthreads();
    #pragma unroll
    for (int kk=0; kk<64; kk+=32){
      bf16x8 pa = *reinterpret_cast<const bf16x8*>(&Ps[w*16 + (lane&15)][kk + (lane>>4)*8]);
      #pragma unroll
      for (int j=0;j<4;j++){
        bf16x8 vb = *reinterpret_cast<const bf16x8*>(&Vt[j*16 + (lane&15)][kk + (lane>>4)*8]);
        acc[j] = __builtin_amdgcn_mfma_f32_16x16x32_bf16(pa, vb, acc[j], 0,0,0);
      }
    }
    __syncthreads();
  }
  #pragma unroll
  for (int j=0;j<4;j++){
    int d = j*16 + (lane&15);
    #pragma unroll
    for (int r=0;r<4;r++){
      int q = qt*64 + w*16 + ((lane>>4)<<2) + r;
      ctx[(size_t)(b*SS + q)*HH + h*DHEAD + d] = f2bf(acc[j][r]);
    }
  }
}

// row LayerNorm, writes f32 (residual path) + bf16 (GEMM A operand); in-place safe
__global__ __launch_bounds__(256) void layernorm_dual(
    const float* __restrict__ x, const float* __restrict__ g, const float* __restrict__ bta,
    float* __restrict__ outF, short* __restrict__ outBF)
{
  const int row = blockIdx.x, t = threadIdx.x;
  const float* xr = x + (size_t)row*HH;
  float v0 = xr[t], v1 = xr[t+256], v2 = xr[t+512];
  float s = v0+v1+v2, q = v0*v0+v1*v1+v2*v2;
  #pragma unroll
  for (int off=32; off>0; off>>=1){ s += __shfl_xor(s,off); q += __shfl_xor(q,off); }
  __shared__ float ss[4], qq[4];
  if ((t&63)==0){ ss[t>>6]=s; qq[t>>6]=q; }
  __syncthreads();
  s = ss[0]+ss[1]+ss[2]+ss[3];
  q = qq[0]+qq[1]+qq[2]+qq[3];
  const float mu = s*(1.0f/HH);
  float var = q*(1.0f/HH) - mu*mu;
  const float rstd = rsqrtf(var + 1e-12f);
  float* oF = outF + (size_t)row*HH;
  short* oB = outBF + (size_t)row*HH;
  float vv[3] = {v0,v1,v2};
  #pragma unroll
  for (int e=0;e<3;e++){
    int c = t + e*256;
    float y = (vv[e]-mu)*rstd*g[c] + bta[c];
    oF[c] = y; oB[c] = f2bf(y);
  }
}

__global__ __launch_bounds__(256) void cvt_f32_bf16(
    const float* __restrict__ in, short* __restrict__ out, int n4)
{
  int i = blockIdx.x*256 + threadIdx.x;
  if (i >= n4) return;
  float4 f = reinterpret_cast<const float4*>(in)[i];
  short4 o; o.x=f2bf(f.x); o.y=f2bf(f.y); o.z=f2bf(f.z); o.w=f2bf(f.w);
  reinterpret_cast<short4*>(out)[i] = o;
}

extern "C" void kernel_launch(void* const* d_in, const int* in_sizes, int n_in,
                              void* d_out, int out_size, void* d_ws, size_t ws_size,
                              hipStream_t stream)
{
  const float* hs   = (const float*)d_in[0];
  const float* mask = (const float*)d_in[1];
  const float* Wq = (const float*)d_in[2];
  const float* bq = (const float*)d_in[3];
  const float* Wk = (const float*)d_in[4];
  const float* bk = (const float*)d_in[5];
  const float* Wv = (const float*)d_in[6];
  const float* bv = (const float*)d_in[7];
  const float* Wo = (const float*)d_in[8];
  const float* bo = (const float*)d_in[9];
  const float* g1 = (const float*)d_in[10];
  const float* b1 = (const float*)d_in[11];
  const float* Wi = (const float*)d_in[12];
  const float* bi = (const float*)d_in[13];
  const float* Wo2= (const float*)d_in[14];
  const float* bo2= (const float*)d_in[15];
  const float* g2 = (const float*)d_in[16];
  const float* b2 = (const float*)d_in[17];

  char* ws = (char*)d_ws;
  size_t off = 0;
  auto alloc = [&](size_t bytes)->char* {
    char* p = ws + off; off += (bytes + 255) & ~(size_t)255; return p;
  };
  float* hf0  = (float*)alloc((size_t)MROWS*HH*4);
  float* hf1  = (float*)alloc((size_t)MROWS*HH*4);
  short* bfA  = (short*)alloc((size_t)MROWS*HH*2);
  short* bfB  = (short*)alloc((size_t)MROWS*HH*2);
  short* QKVb = (short*)alloc((size_t)MROWS*QKVN*2);
  short* Sc   = (short*)alloc((size_t)BB*NHEAD*SS*SS*2);
  short* ctx  = (short*)alloc((size_t)MROWS*HH*2);
  short* inter= (short*)alloc((size_t)MROWS*FFDIM*2);
  short* WqkvT= (short*)alloc((size_t)NLAYER*QKVN*HH*2);
  short* WoT  = (short*)alloc((size_t)NLAYER*HH*HH*2);
  short* WiT  = (short*)alloc((size_t)NLAYER*FFDIM*HH*2);
  short* Wo2T = (short*)alloc((size_t)NLAYER*HH*FFDIM*2);
  float* bqkv = (float*)alloc((size_t)NLAYER*QKVN*4);

  // one-time (per launch) weight prep
  cvt_f32_bf16<<<dim3(3072), 256, 0, stream>>>(hs, bfA, MROWS*HH/4);
  pack_bias<<<dim3((NLAYER*QKVN+255)/256), 256, 0, stream>>>(bq, bk, bv, bqkv);
  transpose_w<<<dim3(12,12,NLAYER), 256, 0, stream>>>(Wq, WqkvT, HH, HH,
      (size_t)HH*HH, (size_t)QKVN*HH, 0);
  transpose_w<<<dim3(12,12,NLAYER), 256, 0, stream>>>(Wk, WqkvT, HH, HH,
      (size_t)HH*HH, (size_t)QKVN*HH, (size_t)HH*HH);
  transpose_w<<<dim3(12,12,NLAYER), 256, 0, stream>>>(Wv, WqkvT, HH, HH,
      (size_t)HH*HH, (size_t)QKVN*HH, (size_t)2*HH*HH);
  transpose_w<<<dim3(12,12,NLAYER), 256, 0, stream>>>(Wo, WoT, HH, HH,
      (size_t)HH*HH, (size_t)HH*HH, 0);
  transpose_w<<<dim3(48,12,NLAYER), 256, 0, stream>>>(Wi, WiT, HH, FFDIM,
      (size_t)HH*FFDIM, (size_t)FFDIM*HH, 0);
  transpose_w<<<dim3(12,48,NLAYER), 256, 0, stream>>>(Wo2, Wo2T, FFDIM, HH,
      (size_t)FFDIM*HH, (size_t)HH*FFDIM, 0);

  const float* curF = hs;
  short* curBF = bfA;
  for (int l=0; l<NLAYER; ++l){
    float* pre1  = (curF == hf0) ? hf1 : hf0;
    short* attBF = (curBF == bfA) ? bfB : bfA;
    size_t vb_ = (size_t)l*HH;

    gemm_tn<128,128,0><<<dim3(32,18), 256, 0, stream>>>(
        curBF, WqkvT + (size_t)l*QKVN*HH, bqkv + (size_t)l*QKVN, nullptr, QKVb,
        MROWS, QKVN, HH);

    attn_scores<<<dim3(8,8,BB*NHEAD), 256, 0, stream>>>(QKVb, QKVb + HH, mask, Sc, QKVN);
    softmax_rows<<<dim3(BB*NHEAD*SS/4), 256, 0, stream>>>(Sc);
    attn_pv<<<dim3(8,BB*NHEAD), 256, 0, stream>>>(Sc, QKVb + 2*HH, ctx, QKVN);

    gemm_tn<128,64,2><<<dim3(32,12), 256, 0, stream>>>(
        ctx, WoT + (size_t)l*HH*HH, bo + vb_, curF, pre1, MROWS, HH, HH);
    layernorm_dual<<<dim3(MROWS), 256, 0, stream>>>(pre1, g1+vb_, b1+vb_, pre1, attBF);

    gemm_tn<128,128,1><<<dim3(32,24), 256, 0, stream>>>(
        attBF, WiT + (size_t)l*FFDIM*HH, bi + (size_t)l*FFDIM, nullptr, inter,
        MROWS, FFDIM, HH);
    float* pre2 = (pre1 == hf0) ? hf1 : hf0;
    gemm_tn<128,64,2><<<dim3(32,12), 256, 0, stream>>>(
        inter, Wo2T + (size_t)l*HH*FFDIM, bo2 + vb_, pre1, pre2, MROWS, HH, FFDIM);

    short* nextBF = (attBF == bfA) ? bfB : bfA;
    float* lnout = (l == NLAYER-1) ? (float*)d_out : pre2;
    layernorm_dual<<<dim3(MROWS), 256, 0, stream>>>(pre2, g2+vb_, b2+vb_, lnout, nextBF);
    curF = lnout; curBF = nextBF;
  }
}